// Round 1
// baseline (312.031 us; speedup 1.0000x reference)
//
#include <hip/hip_runtime.h>

// Problem constants: B=4, S=1024, H=1024, NH=16, DH=64, M=B*S=4096.

typedef __attribute__((ext_vector_type(8))) __bf16 bf16x8;
typedef __attribute__((ext_vector_type(4))) float f32x4;
typedef __attribute__((ext_vector_type(8))) unsigned short u16x8;
typedef __attribute__((ext_vector_type(4))) unsigned short u16x4;

// workspace layout (ushort element offsets)
#define XQ_OFF 0u
#define XK_OFF 4194304u
#define XV_OFF 8388608u
#define WQ_OFF 12582912u
#define WK_OFF 13631488u
#define WV_OFF 14680064u
#define QP_OFF 15728640u
#define KP_OFF 19922944u
#define VP_OFF 24117248u
// total = 28311552 ushorts = 54 MiB

__device__ __forceinline__ unsigned short f2bf(float f) {
  union { float f; unsigned int u; } c; c.f = f;
  return (unsigned short)((c.u + 0x7fffu + ((c.u >> 16) & 1u)) >> 16);  // RNE
}

// ---------------- fp32 -> bf16 conversion of inputs ----------------
__global__ __launch_bounds__(256) void cvt_kernel(
    const float* __restrict__ q, const float* __restrict__ k, const float* __restrict__ v,
    const float* __restrict__ wq, const float* __restrict__ wk, const float* __restrict__ wv,
    unsigned short* __restrict__ ws) {
  const int z = blockIdx.y;
  const float* src; unsigned short* dst; int n;
  switch (z) {
    case 0: src = q;  dst = ws + XQ_OFF; n = 4194304; break;
    case 1: src = k;  dst = ws + XK_OFF; n = 4194304; break;
    case 2: src = v;  dst = ws + XV_OFF; n = 4194304; break;
    case 3: src = wq; dst = ws + WQ_OFF; n = 1048576; break;
    case 4: src = wk; dst = ws + WK_OFF; n = 1048576; break;
    default: src = wv; dst = ws + WV_OFF; n = 1048576; break;
  }
  const int i4 = (blockIdx.x * 256 + threadIdx.x) * 4;
  if (i4 >= n) return;
  const float4 f = *(const float4*)(src + i4);
  u16x4 r;
  r[0] = f2bf(f.x); r[1] = f2bf(f.y); r[2] = f2bf(f.z); r[3] = f2bf(f.w);
  *(u16x4*)(dst + i4) = r;
}

// ---------------- projection GEMM: P = relu(X @ W^T + b), bf16 out ----------------
// X: [4096][1024] bf16 row-major (K contig). W: [1024][1024] bf16 row-major (N x K, K contig).
// m97 pattern: 128x128 tile, BK=32, 4 waves each computing 64x64 (4x4 subtiles of 16x16x32 MFMA).
__global__ __launch_bounds__(256) void proj_gemm(
    const unsigned short* __restrict__ X, const unsigned short* __restrict__ W,
    const float* __restrict__ bias, unsigned short* __restrict__ P) {
  __shared__ unsigned short As[128 * 32];
  __shared__ unsigned short Bs[128 * 32];
  const int tid  = threadIdx.x;
  const int lane = tid & 63;
  const int w    = tid >> 6;
  const int quad = lane >> 4;
  const int l15  = lane & 15;
  const int wr = w >> 1, wc = w & 1;
  const int m0 = blockIdx.y * 128;
  const int n0 = blockIdx.x * 128;

  f32x4 acc[4][4];
#pragma unroll
  for (int i = 0; i < 4; ++i)
#pragma unroll
    for (int j = 0; j < 4; ++j) acc[i][j] = f32x4{0.f, 0.f, 0.f, 0.f};

  for (int kt = 0; kt < 32; ++kt) {
    const int k0 = kt * 32;
    // stage A and B tiles: 512 x 16B chunks each, 2 per thread.
    // chunk c -> row c>>2, k-offset (c&3)*8; LDS dest = wave-uniform base + lane*16 (HW).
#pragma unroll
    for (int pass = 0; pass < 2; ++pass) {
      const int c   = pass * 256 + tid;
      const int row = c >> 2;
      const int kc  = (c & 3) * 8;
      const unsigned short* ga = X + (size_t)(m0 + row) * 1024 + k0 + kc;
      const unsigned short* gb = W + (size_t)(n0 + row) * 1024 + k0 + kc;
      unsigned short* la = &As[(pass * 256 + w * 64) * 8];
      unsigned short* lb = &Bs[(pass * 256 + w * 64) * 8];
      __builtin_amdgcn_global_load_lds((const __attribute__((address_space(1))) void*)ga,
                                       (__attribute__((address_space(3))) void*)la, 16, 0, 0);
      __builtin_amdgcn_global_load_lds((const __attribute__((address_space(1))) void*)gb,
                                       (__attribute__((address_space(3))) void*)lb, 16, 0, 0);
    }
    __syncthreads();
    bf16x8 af[4], bfv[4];
#pragma unroll
    for (int mi = 0; mi < 4; ++mi)
      af[mi] = *(const bf16x8*)&As[(wr * 64 + mi * 16 + l15) * 32 + quad * 8];
#pragma unroll
    for (int ni = 0; ni < 4; ++ni)
      bfv[ni] = *(const bf16x8*)&Bs[(wc * 64 + ni * 16 + l15) * 32 + quad * 8];
#pragma unroll
    for (int mi = 0; mi < 4; ++mi)
#pragma unroll
      for (int ni = 0; ni < 4; ++ni)
        acc[mi][ni] = __builtin_amdgcn_mfma_f32_16x16x32_bf16(af[mi], bfv[ni], acc[mi][ni], 0, 0, 0);
    __syncthreads();
  }
  // epilogue: bias + relu + bf16 store. C/D layout: col=lane&15, row=quad*4+reg (m89-verified).
#pragma unroll
  for (int mi = 0; mi < 4; ++mi)
#pragma unroll
    for (int ni = 0; ni < 4; ++ni) {
      const int col = n0 + wc * 64 + ni * 16 + l15;
      const float bv = bias[col];
#pragma unroll
      for (int r = 0; r < 4; ++r) {
        const int row = m0 + wr * 64 + mi * 16 + quad * 4 + r;
        float v = acc[mi][ni][r] + bv;
        v = v > 0.f ? v : 0.f;
        P[(size_t)row * 1024 + col] = f2bf(v);
      }
    }
}

// ---------------- fused flash attention + mask + residual ----------------
// grid (4, NH, B), block 256 (4 waves). Wave w handles q rows [blockIdx.x*256 + w*64, +64)
// of head blockIdx.y, batch blockIdx.z. Iterates 16 key-blocks of 64 with online softmax.
__global__ __launch_bounds__(256) void attn_kernel(
    const unsigned short* __restrict__ QP, const unsigned short* __restrict__ KP,
    const unsigned short* __restrict__ VP, const float* __restrict__ masks,
    const float* __restrict__ query, float* __restrict__ out) {
  __shared__ unsigned short Kt[64 * 72];       // [key][dh], stride 72 (pad kills row-stride conflicts)
  __shared__ unsigned short Vt[64 * 72];       // [dh][key] transposed, stride 72
  __shared__ unsigned short Pl[4][64 * 72];    // per-wave P tile [q][key], stride 72
  const int tid  = threadIdx.x;
  const int lane = tid & 63;
  const int w    = tid >> 6;
  const int quad = lane >> 4;
  const int l15  = lane & 15;
  const int b = blockIdx.z, h = blockIdx.y;
  const int q0 = blockIdx.x * 256 + w * 64;
  const size_t base = (size_t)b * 1024 * 1024;  // element base of batch b (S*H)

  // Q fragments, resident for the whole kernel. A-layout: A[m=lane&15][k=quad*8+j].
  bf16x8 qf[4][2];
#pragma unroll
  for (int mi = 0; mi < 4; ++mi)
#pragma unroll
    for (int kk = 0; kk < 2; ++kk)
      qf[mi][kk] = *(const bf16x8*)&QP[base + (size_t)(q0 + mi * 16 + l15) * 1024 +
                                       h * 64 + kk * 32 + quad * 8];

  f32x4 o[4][4];
  float mrow[4][4], lrow[4][4];
#pragma unroll
  for (int mi = 0; mi < 4; ++mi) {
#pragma unroll
    for (int nd = 0; nd < 4; ++nd) o[mi][nd] = f32x4{0.f, 0.f, 0.f, 0.f};
#pragma unroll
    for (int r = 0; r < 4; ++r) { mrow[mi][r] = -1e30f; lrow[mi][r] = 0.f; }
  }

  const int krow = tid >> 2;        // 0..63 (key row this thread stages)
  const int d0   = (tid & 3) * 16;  // dh chunk
  const float cvt = 0.18033688011112042f;  // (1/sqrt(64)) * log2(e): softmax in exp2 domain

  for (int kb = 0; kb < 16; ++kb) {
    const int key0 = kb * 64;
    // stage K tile (row-major) and V tile (transposed) into LDS
    {
      const unsigned short* gk = &KP[base + (size_t)(key0 + krow) * 1024 + h * 64 + d0];
      *(u16x8*)&Kt[krow * 72 + d0]     = *(const u16x8*)gk;
      *(u16x8*)&Kt[krow * 72 + d0 + 8] = *(const u16x8*)(gk + 8);
      const unsigned short* gv = &VP[base + (size_t)(key0 + krow) * 1024 + h * 64 + d0];
      u16x8 v0 = *(const u16x8*)gv;
      u16x8 v1 = *(const u16x8*)(gv + 8);
#pragma unroll
      for (int j = 0; j < 8; ++j) {
        Vt[(d0 + j) * 72 + krow]     = v0[j];
        Vt[(d0 + 8 + j) * 72 + krow] = v1[j];
      }
    }
    __syncthreads();

    // S = Q K^T (per mi), then online softmax and P -> LDS (A-layout re-entry)
#pragma unroll
    for (int mi = 0; mi < 4; ++mi) {
      f32x4 s[4];
#pragma unroll
      for (int ni = 0; ni < 4; ++ni) s[ni] = f32x4{0.f, 0.f, 0.f, 0.f};
#pragma unroll
      for (int kk = 0; kk < 2; ++kk)
#pragma unroll
        for (int ni = 0; ni < 4; ++ni) {
          bf16x8 kf = *(const bf16x8*)&Kt[(ni * 16 + l15) * 72 + kk * 32 + quad * 8];
          s[ni] = __builtin_amdgcn_mfma_f32_16x16x32_bf16(qf[mi][kk], kf, s[ni], 0, 0, 0);
        }
      float alpha[4], rowsum[4];
#pragma unroll
      for (int r = 0; r < 4; ++r) {
        float tmax = fmaxf(fmaxf(s[0][r], s[1][r]), fmaxf(s[2][r], s[3][r]));
        tmax = fmaxf(tmax, __shfl_xor(tmax, 1));
        tmax = fmaxf(tmax, __shfl_xor(tmax, 2));
        tmax = fmaxf(tmax, __shfl_xor(tmax, 4));
        tmax = fmaxf(tmax, __shfl_xor(tmax, 8));
        const float mnew = fmaxf(mrow[mi][r], tmax * cvt);
        alpha[r] = exp2f(mrow[mi][r] - mnew);
        mrow[mi][r] = mnew;
        rowsum[r] = 0.f;
      }
#pragma unroll
      for (int ni = 0; ni < 4; ++ni)
#pragma unroll
        for (int r = 0; r < 4; ++r) {
          const float p = exp2f(s[ni][r] * cvt - mrow[mi][r]);
          Pl[w][(mi * 16 + quad * 4 + r) * 72 + ni * 16 + l15] = f2bf(p);
          rowsum[r] += p;
        }
#pragma unroll
      for (int r = 0; r < 4; ++r) {
        float rs = rowsum[r];
        rs += __shfl_xor(rs, 1);
        rs += __shfl_xor(rs, 2);
        rs += __shfl_xor(rs, 4);
        rs += __shfl_xor(rs, 8);
        lrow[mi][r] = lrow[mi][r] * alpha[r] + rs;
#pragma unroll
        for (int nd = 0; nd < 4; ++nd) o[mi][nd][r] *= alpha[r];
      }
    }

    // O += P V  (P from per-wave LDS in A-layout; V^T tile gives K-contiguous B frags)
#pragma unroll
    for (int mi = 0; mi < 4; ++mi)
#pragma unroll
      for (int kk = 0; kk < 2; ++kk) {
        bf16x8 pa = *(const bf16x8*)&Pl[w][(mi * 16 + l15) * 72 + kk * 32 + quad * 8];
#pragma unroll
        for (int nd = 0; nd < 4; ++nd) {
          bf16x8 vf = *(const bf16x8*)&Vt[(nd * 16 + l15) * 72 + kk * 32 + quad * 8];
          o[mi][nd] = __builtin_amdgcn_mfma_f32_16x16x32_bf16(pa, vf, o[mi][nd], 0, 0, 0);
        }
      }
    __syncthreads();
  }

  // epilogue: out = mask[q] * O / l + query   (fp32)
#pragma unroll
  for (int mi = 0; mi < 4; ++mi)
#pragma unroll
    for (int r = 0; r < 4; ++r) {
      const int row = q0 + mi * 16 + quad * 4 + r;
      const float scale = masks[b * 1024 + row] / lrow[mi][r];
#pragma unroll
      for (int nd = 0; nd < 4; ++nd) {
        const int col = h * 64 + nd * 16 + l15;
        const size_t gi = base + (size_t)row * 1024 + col;
        out[gi] = o[mi][nd][r] * scale + query[gi];
      }
    }
}

extern "C" void kernel_launch(void* const* d_in, const int* in_sizes, int n_in,
                              void* d_out, int out_size, void* d_ws, size_t ws_size,
                              hipStream_t stream) {
  const float* q     = (const float*)d_in[0];
  const float* k     = (const float*)d_in[1];
  const float* v     = (const float*)d_in[2];
  const float* masks = (const float*)d_in[3];
  const float* Wq    = (const float*)d_in[4];
  const float* bq    = (const float*)d_in[5];
  const float* Wk    = (const float*)d_in[6];
  const float* bk    = (const float*)d_in[7];
  const float* Wv    = (const float*)d_in[8];
  const float* bv    = (const float*)d_in[9];
  float* out = (float*)d_out;
  unsigned short* ws = (unsigned short*)d_ws;

  cvt_kernel<<<dim3(4096, 6), 256, 0, stream>>>(q, k, v, Wq, Wk, Wv, ws);
  proj_gemm<<<dim3(8, 32), 256, 0, stream>>>(ws + XQ_OFF, ws + WQ_OFF, bq, ws + QP_OFF);
  proj_gemm<<<dim3(8, 32), 256, 0, stream>>>(ws + XK_OFF, ws + WK_OFF, bk, ws + KP_OFF);
  proj_gemm<<<dim3(8, 32), 256, 0, stream>>>(ws + XV_OFF, ws + WV_OFF, bv, ws + VP_OFF);
  attn_kernel<<<dim3(4, 16, 4), 256, 0, stream>>>(ws + QP_OFF, ws + KP_OFF, ws + VP_OFF,
                                                  masks, q, out);
}

// Round 2
// 233.678 us; speedup vs baseline: 1.3353x; 1.3353x over previous
//
#include <hip/hip_runtime.h>

// Problem constants: B=4, S=1024, H=1024, NH=16, DH=64, M=B*S=4096.

typedef __attribute__((ext_vector_type(8))) __bf16 bf16x8;
typedef __attribute__((ext_vector_type(4))) float f32x4;
typedef __attribute__((ext_vector_type(8))) unsigned short u16x8;
typedef __attribute__((ext_vector_type(4))) unsigned short u16x4;

// workspace layout (ushort element offsets)
#define XQ_OFF 0u
#define XK_OFF 4194304u
#define XV_OFF 8388608u
#define WQ_OFF 12582912u
#define WK_OFF 13631488u
#define WV_OFF 14680064u
#define QP_OFF 15728640u
#define KP_OFF 19922944u
#define VT_OFF 24117248u   // V projection stored TRANSPOSED: [b*1024 + h*64 + dh][s]
// total = 28311552 ushorts = 54 MiB

__device__ __forceinline__ unsigned short f2bf(float f) {
  union { float f; unsigned int u; } c; c.f = f;
  return (unsigned short)((c.u + 0x7fffu + ((c.u >> 16) & 1u)) >> 16);  // RNE
}

// ---------------- fp32 -> bf16 conversion of inputs ----------------
__global__ __launch_bounds__(256) void cvt_kernel(
    const float* __restrict__ q, const float* __restrict__ k, const float* __restrict__ v,
    const float* __restrict__ wq, const float* __restrict__ wk, const float* __restrict__ wv,
    unsigned short* __restrict__ ws) {
  const int z = blockIdx.y;
  const float* src; unsigned short* dst; int n;
  switch (z) {
    case 0: src = q;  dst = ws + XQ_OFF; n = 4194304; break;
    case 1: src = k;  dst = ws + XK_OFF; n = 4194304; break;
    case 2: src = v;  dst = ws + XV_OFF; n = 4194304; break;
    case 3: src = wq; dst = ws + WQ_OFF; n = 1048576; break;
    case 4: src = wk; dst = ws + WK_OFF; n = 1048576; break;
    default: src = wv; dst = ws + WV_OFF; n = 1048576; break;
  }
  const int i4 = (blockIdx.x * 256 + threadIdx.x) * 4;
  if (i4 >= n) return;
  const float4 f = *(const float4*)(src + i4);
  u16x4 r;
  r[0] = f2bf(f.x); r[1] = f2bf(f.y); r[2] = f2bf(f.z); r[3] = f2bf(f.w);
  *(u16x4*)(dst + i4) = r;
}

// ---------------- fused projection GEMMs: P = relu(X @ W^T + b), bf16 out ----------------
// blockIdx.z selects {Q,K,V}. m97 pattern: 128x128 tile, BK=32, 4 waves x 64x64.
// z==2 (V): output written TRANSPOSED (VT[b*1024+col][s]) so attention can stage V^T
// with vector loads only (kills round-1's 8-way LDS scatter conflicts).
__global__ __launch_bounds__(256) void proj_gemm(
    unsigned short* __restrict__ ws,
    const float* __restrict__ bq, const float* __restrict__ bk, const float* __restrict__ bv) {
  __shared__ unsigned short As[128 * 32];
  __shared__ unsigned short Bs[128 * 32];
  const int z = blockIdx.z;
  const unsigned short* X = ws + (z == 0 ? XQ_OFF : z == 1 ? XK_OFF : XV_OFF);
  const unsigned short* W = ws + (z == 0 ? WQ_OFF : z == 1 ? WK_OFF : WV_OFF);
  unsigned short* P = ws + (z == 0 ? QP_OFF : z == 1 ? KP_OFF : VT_OFF);
  const float* bias = z == 0 ? bq : z == 1 ? bk : bv;

  const int tid  = threadIdx.x;
  const int lane = tid & 63;
  const int w    = tid >> 6;
  const int quad = lane >> 4;
  const int l15  = lane & 15;
  const int wr = w >> 1, wc = w & 1;
  const int m0 = blockIdx.y * 128;
  const int n0 = blockIdx.x * 128;

  f32x4 acc[4][4];
#pragma unroll
  for (int i = 0; i < 4; ++i)
#pragma unroll
    for (int j = 0; j < 4; ++j) acc[i][j] = f32x4{0.f, 0.f, 0.f, 0.f};

  for (int kt = 0; kt < 32; ++kt) {
    const int k0 = kt * 32;
#pragma unroll
    for (int pass = 0; pass < 2; ++pass) {
      const int c   = pass * 256 + tid;
      const int row = c >> 2;
      const int kc  = (c & 3) * 8;
      const unsigned short* ga = X + (size_t)(m0 + row) * 1024 + k0 + kc;
      const unsigned short* gb = W + (size_t)(n0 + row) * 1024 + k0 + kc;
      unsigned short* la = &As[(pass * 256 + w * 64) * 8];
      unsigned short* lb = &Bs[(pass * 256 + w * 64) * 8];
      __builtin_amdgcn_global_load_lds((const __attribute__((address_space(1))) void*)ga,
                                       (__attribute__((address_space(3))) void*)la, 16, 0, 0);
      __builtin_amdgcn_global_load_lds((const __attribute__((address_space(1))) void*)gb,
                                       (__attribute__((address_space(3))) void*)lb, 16, 0, 0);
    }
    __syncthreads();
    bf16x8 af[4], bfv[4];
#pragma unroll
    for (int mi = 0; mi < 4; ++mi)
      af[mi] = *(const bf16x8*)&As[(wr * 64 + mi * 16 + l15) * 32 + quad * 8];
#pragma unroll
    for (int ni = 0; ni < 4; ++ni)
      bfv[ni] = *(const bf16x8*)&Bs[(wc * 64 + ni * 16 + l15) * 32 + quad * 8];
#pragma unroll
    for (int mi = 0; mi < 4; ++mi)
#pragma unroll
      for (int ni = 0; ni < 4; ++ni)
        acc[mi][ni] = __builtin_amdgcn_mfma_f32_16x16x32_bf16(af[mi], bfv[ni], acc[mi][ni], 0, 0, 0);
    __syncthreads();
  }
  // epilogue: bias + relu + bf16. C/D layout: col=lane&15, row=quad*4+reg (m89-verified).
#pragma unroll
  for (int mi = 0; mi < 4; ++mi)
#pragma unroll
    for (int ni = 0; ni < 4; ++ni) {
      const int col = n0 + wc * 64 + ni * 16 + l15;
      const float bvv = bias[col];
      const int row0 = m0 + wr * 64 + mi * 16 + quad * 4;
      if (z != 2) {
#pragma unroll
        for (int r = 0; r < 4; ++r) {
          float v = acc[mi][ni][r] + bvv;
          v = v > 0.f ? v : 0.f;
          P[(size_t)(row0 + r) * 1024 + col] = f2bf(v);
        }
      } else {
        // transposed: VT[(b*1024 + col)][s], s = row & 1023. 4 consecutive s -> u16x4.
        const int bb = row0 >> 10;
        const int s0 = row0 & 1023;
        u16x4 pk;
#pragma unroll
        for (int r = 0; r < 4; ++r) {
          float v = acc[mi][ni][r] + bvv;
          v = v > 0.f ? v : 0.f;
          pk[r] = f2bf(v);
        }
        *(u16x4*)&P[(size_t)(bb * 1024 + col) * 1024 + s0] = pk;
      }
    }
}

// ---------------- fused flash attention + mask + residual ----------------
// grid (16, NH, B), block 256 (4 waves). Wave w owns 16 q rows: q0 = blockIdx.x*64 + w*16.
// 1024 blocks -> ~5 blocks/CU (LDS 27.6KB), 20 waves/CU.
__global__ __launch_bounds__(256, 5) void attn_kernel(
    const unsigned short* __restrict__ QP, const unsigned short* __restrict__ KP,
    const unsigned short* __restrict__ VT, const float* __restrict__ masks,
    const float* __restrict__ query, float* __restrict__ out) {
  __shared__ unsigned short Kt[64 * 72];     // [key][dh], stride 72
  __shared__ unsigned short Vt[64 * 72];     // [dh][key], stride 72 (staged from VT, vector only)
  __shared__ unsigned short Pl[4][16 * 72];  // per-wave P tile [q][key]
  const int tid  = threadIdx.x;
  const int lane = tid & 63;
  const int w    = tid >> 6;
  const int quad = lane >> 4;
  const int l15  = lane & 15;
  const int b = blockIdx.z, h = blockIdx.y;
  const int q0 = blockIdx.x * 64 + w * 16;
  const size_t base = (size_t)b * 1024 * 1024;

  // Q fragments (A-layout: A[m=lane&15][k=quad*8+j]) for this wave's 16 q rows.
  bf16x8 qf[2];
#pragma unroll
  for (int kk = 0; kk < 2; ++kk)
    qf[kk] = *(const bf16x8*)&QP[base + (size_t)(q0 + l15) * 1024 + h * 64 + kk * 32 + quad * 8];

  f32x4 o[4];
  float mrow[4], lrow[4];
#pragma unroll
  for (int nd = 0; nd < 4; ++nd) o[nd] = f32x4{0.f, 0.f, 0.f, 0.f};
#pragma unroll
  for (int r = 0; r < 4; ++r) { mrow[r] = -1e30f; lrow[r] = 0.f; }

  const int srow = tid >> 2;        // 0..63: key row (K) / dh row (V^T)
  const int c0   = (tid & 3) * 16;  // 16-elem chunk within the 64-wide row
  const float cvt = 0.18033688011112042f;  // (1/sqrt(64)) * log2(e)

  for (int kb = 0; kb < 16; ++kb) {
    const int key0 = kb * 64;
    {
      const unsigned short* gk = &KP[base + (size_t)(key0 + srow) * 1024 + h * 64 + c0];
      *(u16x8*)&Kt[srow * 72 + c0]     = *(const u16x8*)gk;
      *(u16x8*)&Kt[srow * 72 + c0 + 8] = *(const u16x8*)(gk + 8);
      const unsigned short* gv = &VT[(size_t)(b * 1024 + h * 64 + srow) * 1024 + key0 + c0];
      *(u16x8*)&Vt[srow * 72 + c0]     = *(const u16x8*)gv;
      *(u16x8*)&Vt[srow * 72 + c0 + 8] = *(const u16x8*)(gv + 8);
    }
    __syncthreads();

    // S = Q K^T : C-layout rows = q (quad*4+r), cols = key (ni*16+l15)
    f32x4 s[4];
#pragma unroll
    for (int ni = 0; ni < 4; ++ni) s[ni] = f32x4{0.f, 0.f, 0.f, 0.f};
#pragma unroll
    for (int kk = 0; kk < 2; ++kk)
#pragma unroll
      for (int ni = 0; ni < 4; ++ni) {
        bf16x8 kf = *(const bf16x8*)&Kt[(ni * 16 + l15) * 72 + kk * 32 + quad * 8];
        s[ni] = __builtin_amdgcn_mfma_f32_16x16x32_bf16(qf[kk], kf, s[ni], 0, 0, 0);
      }
    float alpha[4];
#pragma unroll
    for (int r = 0; r < 4; ++r) {
      float tmax = fmaxf(fmaxf(s[0][r], s[1][r]), fmaxf(s[2][r], s[3][r]));
      tmax = fmaxf(tmax, __shfl_xor(tmax, 1));
      tmax = fmaxf(tmax, __shfl_xor(tmax, 2));
      tmax = fmaxf(tmax, __shfl_xor(tmax, 4));
      tmax = fmaxf(tmax, __shfl_xor(tmax, 8));
      const float mnew = fmaxf(mrow[r], tmax * cvt);
      alpha[r] = exp2f(mrow[r] - mnew);
      mrow[r] = mnew;
    }
    float rowsum[4] = {0.f, 0.f, 0.f, 0.f};
#pragma unroll
    for (int ni = 0; ni < 4; ++ni)
#pragma unroll
      for (int r = 0; r < 4; ++r) {
        const float p = exp2f(s[ni][r] * cvt - mrow[r]);
        Pl[w][(quad * 4 + r) * 72 + ni * 16 + l15] = f2bf(p);
        rowsum[r] += p;
      }
#pragma unroll
    for (int r = 0; r < 4; ++r) {
      float rs = rowsum[r];
      rs += __shfl_xor(rs, 1);
      rs += __shfl_xor(rs, 2);
      rs += __shfl_xor(rs, 4);
      rs += __shfl_xor(rs, 8);
      lrow[r] = lrow[r] * alpha[r] + rs;
#pragma unroll
      for (int nd = 0; nd < 4; ++nd) o[nd][r] *= alpha[r];
    }

    // O += P V  (P re-enters in A-layout from per-wave LDS; V^T gives K-contig B frags)
#pragma unroll
    for (int kk = 0; kk < 2; ++kk) {
      bf16x8 pa = *(const bf16x8*)&Pl[w][l15 * 72 + kk * 32 + quad * 8];
#pragma unroll
      for (int nd = 0; nd < 4; ++nd) {
        bf16x8 vf = *(const bf16x8*)&Vt[(nd * 16 + l15) * 72 + kk * 32 + quad * 8];
        o[nd] = __builtin_amdgcn_mfma_f32_16x16x32_bf16(pa, vf, o[nd], 0, 0, 0);
      }
    }
    __syncthreads();
  }

  // epilogue: out = mask[q] * O / l + query   (fp32)
#pragma unroll
  for (int r = 0; r < 4; ++r) {
    const int row = q0 + quad * 4 + r;
    const float scale = masks[b * 1024 + row] / lrow[r];
#pragma unroll
    for (int nd = 0; nd < 4; ++nd) {
      const int col = h * 64 + nd * 16 + l15;
      const size_t gi = base + (size_t)row * 1024 + col;
      out[gi] = o[nd][r] * scale + query[gi];
    }
  }
}

extern "C" void kernel_launch(void* const* d_in, const int* in_sizes, int n_in,
                              void* d_out, int out_size, void* d_ws, size_t ws_size,
                              hipStream_t stream) {
  const float* q     = (const float*)d_in[0];
  const float* k     = (const float*)d_in[1];
  const float* v     = (const float*)d_in[2];
  const float* masks = (const float*)d_in[3];
  const float* bq    = (const float*)d_in[5];
  const float* bk    = (const float*)d_in[7];
  const float* bv    = (const float*)d_in[9];
  const float* Wq    = (const float*)d_in[4];
  const float* Wk    = (const float*)d_in[6];
  const float* Wv    = (const float*)d_in[8];
  float* out = (float*)d_out;
  unsigned short* ws = (unsigned short*)d_ws;

  cvt_kernel<<<dim3(4096, 6), 256, 0, stream>>>(q, k, v, Wq, Wk, Wv, ws);
  proj_gemm<<<dim3(8, 32, 3), 256, 0, stream>>>(ws, bq, bk, bv);
  attn_kernel<<<dim3(16, 16, 4), 256, 0, stream>>>(ws + QP_OFF, ws + KP_OFF, ws + VT_OFF,
                                                   masks, q, out);
}

// Round 3
// 207.064 us; speedup vs baseline: 1.5069x; 1.1285x over previous
//
#include <hip/hip_runtime.h>

// Problem constants: B=4, S=1024, H=1024, NH=16, DH=64, M=B*S=4096.

typedef __attribute__((ext_vector_type(8))) __bf16 bf16x8;
typedef __attribute__((ext_vector_type(4))) float f32x4;
typedef __attribute__((ext_vector_type(8))) unsigned short u16x8;
typedef __attribute__((ext_vector_type(4))) unsigned short u16x4;

// workspace layout (ushort element offsets)
#define XQ_OFF 0u
#define XK_OFF 4194304u
#define XV_OFF 8388608u
#define WQ_OFF 12582912u
#define WK_OFF 13631488u
#define WV_OFF 14680064u
#define QP_OFF 15728640u
#define KP_OFF 19922944u
#define VP_OFF 24117248u   // row-major again (r2's transposed write scattered 8B stores)
// total = 28311552 ushorts = 54 MiB

__device__ __forceinline__ unsigned short f2bf(float f) {
  union { float f; unsigned int u; } c; c.f = f;
  return (unsigned short)((c.u + 0x7fffu + ((c.u >> 16) & 1u)) >> 16);  // RNE
}

// ---------------- fp32 -> bf16 conversion of inputs ----------------
__global__ __launch_bounds__(256) void cvt_kernel(
    const float* __restrict__ q, const float* __restrict__ k, const float* __restrict__ v,
    const float* __restrict__ wq, const float* __restrict__ wk, const float* __restrict__ wv,
    unsigned short* __restrict__ ws) {
  const int z = blockIdx.y;
  const float* src; unsigned short* dst; int n;
  switch (z) {
    case 0: src = q;  dst = ws + XQ_OFF; n = 4194304; break;
    case 1: src = k;  dst = ws + XK_OFF; n = 4194304; break;
    case 2: src = v;  dst = ws + XV_OFF; n = 4194304; break;
    case 3: src = wq; dst = ws + WQ_OFF; n = 1048576; break;
    case 4: src = wk; dst = ws + WK_OFF; n = 1048576; break;
    default: src = wv; dst = ws + WV_OFF; n = 1048576; break;
  }
  const int i8 = (blockIdx.x * 256 + threadIdx.x) * 8;
  if (i8 >= n) return;
  const float4 f0 = *(const float4*)(src + i8);
  const float4 f1 = *(const float4*)(src + i8 + 4);
  u16x8 r;
  r[0] = f2bf(f0.x); r[1] = f2bf(f0.y); r[2] = f2bf(f0.z); r[3] = f2bf(f0.w);
  r[4] = f2bf(f1.x); r[5] = f2bf(f1.y); r[6] = f2bf(f1.z); r[7] = f2bf(f1.w);
  *(u16x8*)(dst + i8) = r;
}

// ---------------- fused projection GEMMs: P = relu(X @ W^T + b), bf16 out ----------------
// blockIdx.z selects {Q,K,V}. m97 pattern: 128x128 tile, BK=32, 4 waves x 64x64.
// All outputs row-major [s][h] with coalesced epilogue stores.
__global__ __launch_bounds__(256) void proj_gemm(
    unsigned short* __restrict__ ws,
    const float* __restrict__ bq, const float* __restrict__ bk, const float* __restrict__ bv) {
  __shared__ unsigned short As[128 * 32];
  __shared__ unsigned short Bs[128 * 32];
  const int z = blockIdx.z;
  const unsigned short* X = ws + (z == 0 ? XQ_OFF : z == 1 ? XK_OFF : XV_OFF);
  const unsigned short* W = ws + (z == 0 ? WQ_OFF : z == 1 ? WK_OFF : WV_OFF);
  unsigned short* P = ws + (z == 0 ? QP_OFF : z == 1 ? KP_OFF : VP_OFF);
  const float* bias = z == 0 ? bq : z == 1 ? bk : bv;

  const int tid  = threadIdx.x;
  const int lane = tid & 63;
  const int w    = tid >> 6;
  const int quad = lane >> 4;
  const int l15  = lane & 15;
  const int wr = w >> 1, wc = w & 1;
  const int m0 = blockIdx.y * 128;
  const int n0 = blockIdx.x * 128;

  f32x4 acc[4][4];
#pragma unroll
  for (int i = 0; i < 4; ++i)
#pragma unroll
    for (int j = 0; j < 4; ++j) acc[i][j] = f32x4{0.f, 0.f, 0.f, 0.f};

  for (int kt = 0; kt < 32; ++kt) {
    const int k0 = kt * 32;
#pragma unroll
    for (int pass = 0; pass < 2; ++pass) {
      const int c   = pass * 256 + tid;
      const int row = c >> 2;
      const int kc  = (c & 3) * 8;
      const unsigned short* ga = X + (size_t)(m0 + row) * 1024 + k0 + kc;
      const unsigned short* gb = W + (size_t)(n0 + row) * 1024 + k0 + kc;
      unsigned short* la = &As[(pass * 256 + w * 64) * 8];
      unsigned short* lb = &Bs[(pass * 256 + w * 64) * 8];
      __builtin_amdgcn_global_load_lds((const __attribute__((address_space(1))) void*)ga,
                                       (__attribute__((address_space(3))) void*)la, 16, 0, 0);
      __builtin_amdgcn_global_load_lds((const __attribute__((address_space(1))) void*)gb,
                                       (__attribute__((address_space(3))) void*)lb, 16, 0, 0);
    }
    __syncthreads();
    bf16x8 af[4], bfv[4];
#pragma unroll
    for (int mi = 0; mi < 4; ++mi)
      af[mi] = *(const bf16x8*)&As[(wr * 64 + mi * 16 + l15) * 32 + quad * 8];
#pragma unroll
    for (int ni = 0; ni < 4; ++ni)
      bfv[ni] = *(const bf16x8*)&Bs[(wc * 64 + ni * 16 + l15) * 32 + quad * 8];
#pragma unroll
    for (int mi = 0; mi < 4; ++mi)
#pragma unroll
      for (int ni = 0; ni < 4; ++ni)
        acc[mi][ni] = __builtin_amdgcn_mfma_f32_16x16x32_bf16(af[mi], bfv[ni], acc[mi][ni], 0, 0, 0);
    __syncthreads();
  }
  // epilogue: bias + relu + bf16. C/D layout: col=lane&15, row=quad*4+reg (m89-verified).
#pragma unroll
  for (int mi = 0; mi < 4; ++mi)
#pragma unroll
    for (int ni = 0; ni < 4; ++ni) {
      const int col = n0 + wc * 64 + ni * 16 + l15;
      const float bvv = bias[col];
      const int row0 = m0 + wr * 64 + mi * 16 + quad * 4;
#pragma unroll
      for (int r = 0; r < 4; ++r) {
        float v = acc[mi][ni][r] + bvv;
        v = v > 0.f ? v : 0.f;
        P[(size_t)(row0 + r) * 1024 + col] = f2bf(v);
      }
    }
}

// ---------------- fused flash attention + mask + residual ----------------
// grid (8, NH, B), block 512 (8 waves). Wave w owns 16 q rows: q0 = blockIdx.x*128 + w*16.
// 512 blocks, LDS 36.9KB -> 4 blocks/CU, 32 waves/CU.
// Softmax with FIXED shift: scores = qh.kh/8 >= 0 (ReLU outputs), max ~4 << 96
// (overflow bound), so p = exp2(s*cvt - 8) is exact softmax math (shift cancels in p/sum).
// No running max, no rescale; row-sum reduced once at the end.
__global__ __launch_bounds__(512, 8) void attn_kernel(
    const unsigned short* __restrict__ QP, const unsigned short* __restrict__ KP,
    const unsigned short* __restrict__ VP, const float* __restrict__ masks,
    const float* __restrict__ query, float* __restrict__ out) {
  __shared__ unsigned short Kt[64 * 72];     // [key][dh], stride 72
  __shared__ unsigned short Vt[64 * 72];     // [dh][key], stride 72
  __shared__ unsigned short Pl[8][16 * 72];  // per-wave P tile [q][key]
  const int tid  = threadIdx.x;
  const int lane = tid & 63;
  const int w    = tid >> 6;
  const int quad = lane >> 4;
  const int l15  = lane & 15;
  const int b = blockIdx.z, h = blockIdx.y;
  const int q0 = blockIdx.x * 128 + w * 16;
  const size_t base = (size_t)b * 1024 * 1024;

  // Q fragments (A-layout: A[m=lane&15][k=quad*8+j]) for this wave's 16 q rows.
  bf16x8 qf[2];
#pragma unroll
  for (int kk = 0; kk < 2; ++kk)
    qf[kk] = *(const bf16x8*)&QP[base + (size_t)(q0 + l15) * 1024 + h * 64 + kk * 32 + quad * 8];

  f32x4 o[4];
  float lsum[4];
#pragma unroll
  for (int nd = 0; nd < 4; ++nd) o[nd] = f32x4{0.f, 0.f, 0.f, 0.f};
#pragma unroll
  for (int r = 0; r < 4; ++r) lsum[r] = 0.f;

  const int srow = tid >> 3;        // 0..63: key row
  const int c0   = (tid & 3 + 0, (tid & 7) * 8);  // 8-elem chunk within 64-wide row
  const float cvt = 0.18033688011112042f;  // (1/sqrt(64)) * log2(e)

  for (int kb = 0; kb < 16; ++kb) {
    const int key0 = kb * 64;
    {
      const unsigned short* gk = &KP[base + (size_t)(key0 + srow) * 1024 + h * 64 + c0];
      *(u16x8*)&Kt[srow * 72 + c0] = *(const u16x8*)gk;
      const u16x8 v8 = *(const u16x8*)&VP[base + (size_t)(key0 + srow) * 1024 + h * 64 + c0];
#pragma unroll
      for (int j = 0; j < 8; ++j) Vt[(c0 + j) * 72 + srow] = v8[j];
    }
    __syncthreads();

    // S = Q K^T : C-layout rows = q (quad*4+r), cols = key (ni*16+l15)
    f32x4 s[4];
#pragma unroll
    for (int ni = 0; ni < 4; ++ni) s[ni] = f32x4{0.f, 0.f, 0.f, 0.f};
#pragma unroll
    for (int kk = 0; kk < 2; ++kk)
#pragma unroll
      for (int ni = 0; ni < 4; ++ni) {
        bf16x8 kf = *(const bf16x8*)&Kt[(ni * 16 + l15) * 72 + kk * 32 + quad * 8];
        s[ni] = __builtin_amdgcn_mfma_f32_16x16x32_bf16(qf[kk], kf, s[ni], 0, 0, 0);
      }
    // fixed-shift exp; P -> per-wave LDS for A-layout re-entry
#pragma unroll
    for (int ni = 0; ni < 4; ++ni)
#pragma unroll
      for (int r = 0; r < 4; ++r) {
        const float p = exp2f(s[ni][r] * cvt - 8.0f);
        Pl[w][(quad * 4 + r) * 72 + ni * 16 + l15] = f2bf(p);
        lsum[r] += p;
      }

    // O += P V
#pragma unroll
    for (int kk = 0; kk < 2; ++kk) {
      bf16x8 pa = *(const bf16x8*)&Pl[w][l15 * 72 + kk * 32 + quad * 8];
#pragma unroll
      for (int nd = 0; nd < 4; ++nd) {
        bf16x8 vf = *(const bf16x8*)&Vt[(nd * 16 + l15) * 72 + kk * 32 + quad * 8];
        o[nd] = __builtin_amdgcn_mfma_f32_16x16x32_bf16(pa, vf, o[nd], 0, 0, 0);
      }
    }
    __syncthreads();
  }

  // single deferred row-sum reduction (over the 16 l15 lanes of each row)
#pragma unroll
  for (int r = 0; r < 4; ++r) {
    float rs = lsum[r];
    rs += __shfl_xor(rs, 1);
    rs += __shfl_xor(rs, 2);
    rs += __shfl_xor(rs, 4);
    rs += __shfl_xor(rs, 8);
    lsum[r] = rs;
  }

  // epilogue: out = mask[q] * O / l + query   (fp32)
#pragma unroll
  for (int r = 0; r < 4; ++r) {
    const int row = q0 + quad * 4 + r;
    const float scale = masks[b * 1024 + row] / lsum[r];
#pragma unroll
    for (int nd = 0; nd < 4; ++nd) {
      const int col = h * 64 + nd * 16 + l15;
      const size_t gi = base + (size_t)row * 1024 + col;
      out[gi] = o[nd][r] * scale + query[gi];
    }
  }
}

extern "C" void kernel_launch(void* const* d_in, const int* in_sizes, int n_in,
                              void* d_out, int out_size, void* d_ws, size_t ws_size,
                              hipStream_t stream) {
  const float* q     = (const float*)d_in[0];
  const float* k     = (const float*)d_in[1];
  const float* v     = (const float*)d_in[2];
  const float* masks = (const float*)d_in[3];
  const float* Wq    = (const float*)d_in[4];
  const float* bq    = (const float*)d_in[5];
  const float* Wk    = (const float*)d_in[6];
  const float* bk    = (const float*)d_in[7];
  const float* Wv    = (const float*)d_in[8];
  const float* bv    = (const float*)d_in[9];
  float* out = (float*)d_out;
  unsigned short* ws = (unsigned short*)d_ws;

  cvt_kernel<<<dim3(2048, 6), 256, 0, stream>>>(q, k, v, Wq, Wk, Wv, ws);
  proj_gemm<<<dim3(8, 32, 3), 256, 0, stream>>>(ws, bq, bk, bv);
  attn_kernel<<<dim3(8, 16, 4), 512, 0, stream>>>(ws + QP_OFF, ws + KP_OFF, ws + VP_OFF,
                                                  masks, q, out);
}

// Round 4
// 205.482 us; speedup vs baseline: 1.5185x; 1.0077x over previous
//
#include <hip/hip_runtime.h>

// Problem constants: B=4, S=1024, H=1024, NH=16, DH=64, M=B*S=4096.

typedef __attribute__((ext_vector_type(8))) __bf16 bf16x8;
typedef __attribute__((ext_vector_type(4))) float f32x4;
typedef __attribute__((ext_vector_type(8))) unsigned short u16x8;
typedef __attribute__((ext_vector_type(4))) unsigned short u16x4;

// workspace layout (ushort element offsets)
#define XQ_OFF 0u
#define XK_OFF 4194304u
#define XV_OFF 8388608u
#define WQ_OFF 12582912u
#define WK_OFF 13631488u
#define WV_OFF 14680064u
#define QP_OFF 15728640u
#define KP_OFF 19922944u
#define VP_OFF 24117248u   // row-major [b][s][h]
#define VT_OFF 28311552u   // transposed [(b*16+h)*64+dh][s]
// total = 32505856 ushorts = 62 MiB

__device__ __forceinline__ unsigned short f2bf(float f) {
  union { float f; unsigned int u; } c; c.f = f;
  return (unsigned short)((c.u + 0x7fffu + ((c.u >> 16) & 1u)) >> 16);  // RNE
}

// ---------------- fp32 -> bf16 conversion of inputs ----------------
__global__ __launch_bounds__(256) void cvt_kernel(
    const float* __restrict__ q, const float* __restrict__ k, const float* __restrict__ v,
    const float* __restrict__ wq, const float* __restrict__ wk, const float* __restrict__ wv,
    unsigned short* __restrict__ ws) {
  const int z = blockIdx.y;
  const float* src; unsigned short* dst; int n;
  switch (z) {
    case 0: src = q;  dst = ws + XQ_OFF; n = 4194304; break;
    case 1: src = k;  dst = ws + XK_OFF; n = 4194304; break;
    case 2: src = v;  dst = ws + XV_OFF; n = 4194304; break;
    case 3: src = wq; dst = ws + WQ_OFF; n = 1048576; break;
    case 4: src = wk; dst = ws + WK_OFF; n = 1048576; break;
    default: src = wv; dst = ws + WV_OFF; n = 1048576; break;
  }
  const int i8 = (blockIdx.x * 256 + threadIdx.x) * 8;
  if (i8 >= n) return;
  const float4 f0 = *(const float4*)(src + i8);
  const float4 f1 = *(const float4*)(src + i8 + 4);
  u16x8 r;
  r[0] = f2bf(f0.x); r[1] = f2bf(f0.y); r[2] = f2bf(f0.z); r[3] = f2bf(f0.w);
  r[4] = f2bf(f1.x); r[5] = f2bf(f1.y); r[6] = f2bf(f1.z); r[7] = f2bf(f1.w);
  *(u16x8*)(dst + i8) = r;
}

// ---------------- fused projection GEMMs: P = relu(X @ W^T + b), bf16 out ----------------
__global__ __launch_bounds__(256) void proj_gemm(
    unsigned short* __restrict__ ws,
    const float* __restrict__ bq, const float* __restrict__ bk, const float* __restrict__ bv) {
  __shared__ unsigned short As[128 * 32];
  __shared__ unsigned short Bs[128 * 32];
  const int z = blockIdx.z;
  const unsigned short* X = ws + (z == 0 ? XQ_OFF : z == 1 ? XK_OFF : XV_OFF);
  const unsigned short* W = ws + (z == 0 ? WQ_OFF : z == 1 ? WK_OFF : WV_OFF);
  unsigned short* P = ws + (z == 0 ? QP_OFF : z == 1 ? KP_OFF : VP_OFF);
  const float* bias = z == 0 ? bq : z == 1 ? bk : bv;

  const int tid  = threadIdx.x;
  const int lane = tid & 63;
  const int w    = tid >> 6;
  const int quad = lane >> 4;
  const int l15  = lane & 15;
  const int wr = w >> 1, wc = w & 1;
  const int m0 = blockIdx.y * 128;
  const int n0 = blockIdx.x * 128;

  f32x4 acc[4][4];
#pragma unroll
  for (int i = 0; i < 4; ++i)
#pragma unroll
    for (int j = 0; j < 4; ++j) acc[i][j] = f32x4{0.f, 0.f, 0.f, 0.f};

  for (int kt = 0; kt < 32; ++kt) {
    const int k0 = kt * 32;
#pragma unroll
    for (int pass = 0; pass < 2; ++pass) {
      const int c   = pass * 256 + tid;
      const int row = c >> 2;
      const int kc  = (c & 3) * 8;
      const unsigned short* ga = X + (size_t)(m0 + row) * 1024 + k0 + kc;
      const unsigned short* gb = W + (size_t)(n0 + row) * 1024 + k0 + kc;
      unsigned short* la = &As[(pass * 256 + w * 64) * 8];
      unsigned short* lb = &Bs[(pass * 256 + w * 64) * 8];
      __builtin_amdgcn_global_load_lds((const __attribute__((address_space(1))) void*)ga,
                                       (__attribute__((address_space(3))) void*)la, 16, 0, 0);
      __builtin_amdgcn_global_load_lds((const __attribute__((address_space(1))) void*)gb,
                                       (__attribute__((address_space(3))) void*)lb, 16, 0, 0);
    }
    __syncthreads();
    bf16x8 af[4], bfv[4];
#pragma unroll
    for (int mi = 0; mi < 4; ++mi)
      af[mi] = *(const bf16x8*)&As[(wr * 64 + mi * 16 + l15) * 32 + quad * 8];
#pragma unroll
    for (int ni = 0; ni < 4; ++ni)
      bfv[ni] = *(const bf16x8*)&Bs[(wc * 64 + ni * 16 + l15) * 32 + quad * 8];
#pragma unroll
    for (int mi = 0; mi < 4; ++mi)
#pragma unroll
      for (int ni = 0; ni < 4; ++ni)
        acc[mi][ni] = __builtin_amdgcn_mfma_f32_16x16x32_bf16(af[mi], bfv[ni], acc[mi][ni], 0, 0, 0);
    __syncthreads();
  }
#pragma unroll
  for (int mi = 0; mi < 4; ++mi)
#pragma unroll
    for (int ni = 0; ni < 4; ++ni) {
      const int col = n0 + wc * 64 + ni * 16 + l15;
      const float bvv = bias[col];
      const int row0 = m0 + wr * 64 + mi * 16 + quad * 4;
#pragma unroll
      for (int r = 0; r < 4; ++r) {
        float v = acc[mi][ni][r] + bvv;
        v = v > 0.f ? v : 0.f;
        P[(size_t)(row0 + r) * 1024 + col] = f2bf(v);
      }
    }
}

// ---------------- V transpose: VP [b][s][h] -> VT [(b*16+h)*64+dh][s] ----------------
// 64x64 tiles through LDS; coalesced global on both sides; j-rotation keeps LDS
// gather at ~2-way conflicts (free per m136).
__global__ __launch_bounds__(256) void vtrans_kernel(
    const unsigned short* __restrict__ VP, unsigned short* __restrict__ VT) {
  __shared__ unsigned short T[64 * 72];
  const int tid = threadIdx.x;
  const int bh = blockIdx.y;            // b*16+h
  const int b = bh >> 4, h = bh & 15;
  const int s0 = blockIdx.x * 64;
  const int rr = tid >> 2;              // 0..63
  const int cc = (tid & 3) * 16;
  {
    const unsigned short* g = &VP[(size_t)(b * 1024 + s0 + rr) * 1024 + h * 64 + cc];
    *(u16x8*)&T[rr * 72 + cc]     = *(const u16x8*)g;
    *(u16x8*)&T[rr * 72 + cc + 8] = *(const u16x8*)(g + 8);
  }
  __syncthreads();
  {
    // thread writes dh-row rr, key chunk cc..cc+15
    unsigned short o[16];
#pragma unroll
    for (int jj = 0; jj < 16; ++jj) {
      const int j = (jj + (tid & 3) * 4) & 15;   // rotate to spread banks
      o[j] = T[(cc + j) * 72 + rr];
    }
    unsigned short* g = &VT[(size_t)(bh * 64 + rr) * 1024 + s0 + cc];
    *(u16x8*)g       = *(const u16x8*)&o[0];
    *(u16x8*)(g + 8) = *(const u16x8*)&o[8];
  }
}

// ---------------- fused flash attention + mask + residual ----------------
// grid (8, NH, B), block 256 (4 waves). Wave w owns 32 q rows (2 m-subtiles):
// q0w = blockIdx.x*128 + w*32. B-fragments (K, V^T) reused across both m-subtiles
// -> ~45% fewer ds_read_b128 per q-row than r3. Clean Vt staging from VT (no scatter).
// Fixed-shift softmax (scores >= 0 from ReLU): p = exp2(s*cvt - 8), exact.
__global__ __launch_bounds__(256, 2) void attn_kernel(
    const unsigned short* __restrict__ QP, const unsigned short* __restrict__ KP,
    const unsigned short* __restrict__ VT, const float* __restrict__ masks,
    const float* __restrict__ query, float* __restrict__ out) {
  __shared__ unsigned short Kt[64 * 72];     // [key][dh]
  __shared__ unsigned short Vt[64 * 72];     // [dh][key]
  __shared__ unsigned short Pl[4][32 * 72];  // per-wave P tile [q(32)][key]
  const int tid  = threadIdx.x;
  const int lane = tid & 63;
  const int w    = tid >> 6;
  const int quad = lane >> 4;
  const int l15  = lane & 15;
  const int b = blockIdx.z, h = blockIdx.y;
  const int q0w = blockIdx.x * 128 + w * 32;
  const size_t base = (size_t)b * 1024 * 1024;
  const int bh = b * 16 + h;

  // Q fragments (A-layout) for 2 m-subtiles x 2 k-halves
  bf16x8 qf[2][2];
#pragma unroll
  for (int mt = 0; mt < 2; ++mt)
#pragma unroll
    for (int kk = 0; kk < 2; ++kk)
      qf[mt][kk] = *(const bf16x8*)&QP[base + (size_t)(q0w + mt * 16 + l15) * 1024 +
                                       h * 64 + kk * 32 + quad * 8];

  f32x4 o[2][4];
  float lsum[2][4];
#pragma unroll
  for (int mt = 0; mt < 2; ++mt)
#pragma unroll
    for (int nd = 0; nd < 4; ++nd) o[mt][nd] = f32x4{0.f, 0.f, 0.f, 0.f};
#pragma unroll
  for (int mt = 0; mt < 2; ++mt)
#pragma unroll
    for (int r = 0; r < 4; ++r) lsum[mt][r] = 0.f;

  const int srow = tid >> 2;        // 0..63: key row (Kt) / dh row (Vt)
  const int c0   = (tid & 3) * 16;
  const float cvt = 0.18033688011112042f;  // (1/sqrt(64)) * log2(e)

  for (int kb = 0; kb < 16; ++kb) {
    const int key0 = kb * 64;
    {
      const unsigned short* gk = &KP[base + (size_t)(key0 + srow) * 1024 + h * 64 + c0];
      *(u16x8*)&Kt[srow * 72 + c0]     = *(const u16x8*)gk;
      *(u16x8*)&Kt[srow * 72 + c0 + 8] = *(const u16x8*)(gk + 8);
      const unsigned short* gv = &VT[(size_t)(bh * 64 + srow) * 1024 + key0 + c0];
      *(u16x8*)&Vt[srow * 72 + c0]     = *(const u16x8*)gv;
      *(u16x8*)&Vt[srow * 72 + c0 + 8] = *(const u16x8*)(gv + 8);
    }
    __syncthreads();

    // S = Q K^T for both m-subtiles; kf frags shared across mt
#pragma unroll
    for (int mt = 0; mt < 2; ++mt) {
      f32x4 s[4];
#pragma unroll
      for (int ni = 0; ni < 4; ++ni) s[ni] = f32x4{0.f, 0.f, 0.f, 0.f};
#pragma unroll
      for (int kk = 0; kk < 2; ++kk)
#pragma unroll
        for (int ni = 0; ni < 4; ++ni) {
          bf16x8 kf = *(const bf16x8*)&Kt[(ni * 16 + l15) * 72 + kk * 32 + quad * 8];
          s[ni] = __builtin_amdgcn_mfma_f32_16x16x32_bf16(qf[mt][kk], kf, s[ni], 0, 0, 0);
        }
#pragma unroll
      for (int ni = 0; ni < 4; ++ni)
#pragma unroll
        for (int r = 0; r < 4; ++r) {
          const float p = exp2f(s[ni][r] * cvt - 8.0f);
          Pl[w][(mt * 16 + quad * 4 + r) * 72 + ni * 16 + l15] = f2bf(p);
          lsum[mt][r] += p;
        }
    }

    // O += P V ; vf frags shared across mt
#pragma unroll
    for (int kk = 0; kk < 2; ++kk) {
      bf16x8 pa[2];
#pragma unroll
      for (int mt = 0; mt < 2; ++mt)
        pa[mt] = *(const bf16x8*)&Pl[w][(mt * 16 + l15) * 72 + kk * 32 + quad * 8];
#pragma unroll
      for (int nd = 0; nd < 4; ++nd) {
        bf16x8 vf = *(const bf16x8*)&Vt[(nd * 16 + l15) * 72 + kk * 32 + quad * 8];
#pragma unroll
        for (int mt = 0; mt < 2; ++mt)
          o[mt][nd] = __builtin_amdgcn_mfma_f32_16x16x32_bf16(pa[mt], vf, o[mt][nd], 0, 0, 0);
      }
    }
    __syncthreads();
  }

  // deferred row-sum reduction + epilogue
#pragma unroll
  for (int mt = 0; mt < 2; ++mt) {
#pragma unroll
    for (int r = 0; r < 4; ++r) {
      float rs = lsum[mt][r];
      rs += __shfl_xor(rs, 1);
      rs += __shfl_xor(rs, 2);
      rs += __shfl_xor(rs, 4);
      rs += __shfl_xor(rs, 8);
      const int row = q0w + mt * 16 + quad * 4 + r;
      const float scale = masks[b * 1024 + row] / rs;
#pragma unroll
      for (int nd = 0; nd < 4; ++nd) {
        const int col = h * 64 + nd * 16 + l15;
        const size_t gi = base + (size_t)row * 1024 + col;
        out[gi] = o[mt][nd][r] * scale + query[gi];
      }
    }
  }
}

extern "C" void kernel_launch(void* const* d_in, const int* in_sizes, int n_in,
                              void* d_out, int out_size, void* d_ws, size_t ws_size,
                              hipStream_t stream) {
  const float* q     = (const float*)d_in[0];
  const float* k     = (const float*)d_in[1];
  const float* v     = (const float*)d_in[2];
  const float* masks = (const float*)d_in[3];
  const float* Wq    = (const float*)d_in[4];
  const float* bq    = (const float*)d_in[5];
  const float* Wk    = (const float*)d_in[6];
  const float* bk    = (const float*)d_in[7];
  const float* Wv    = (const float*)d_in[8];
  const float* bv    = (const float*)d_in[9];
  float* out = (float*)d_out;
  unsigned short* ws = (unsigned short*)d_ws;

  cvt_kernel<<<dim3(2048, 6), 256, 0, stream>>>(q, k, v, Wq, Wk, Wv, ws);
  proj_gemm<<<dim3(8, 32, 3), 256, 0, stream>>>(ws, bq, bk, bv);
  vtrans_kernel<<<dim3(16, 64), 256, 0, stream>>>(ws + VP_OFF, ws + VT_OFF);
  attn_kernel<<<dim3(8, 16, 4), 256, 0, stream>>>(ws + QP_OFF, ws + KP_OFF, ws + VT_OFF,
                                                  masks, q, out);
}